// Round 1
// baseline (718.234 us; speedup 1.0000x reference)
//
#include <hip/hip_runtime.h>
#include <stdint.h>

typedef unsigned short u16;
typedef __attribute__((ext_vector_type(4))) float f32x4;
typedef __attribute__((ext_vector_type(8))) short bf16x8;

static constexpr int S   = 2048;
static constexpr int DM  = 4096;  // model dim
static constexpr int NH  = 32;    // query heads
static constexpr int NKV = 8;     // kv heads
static constexpr int HD  = 128;   // head dim

__device__ __forceinline__ u16 f2bf(float f) {
    union { float f; unsigned u; } v; v.f = f;
    return (u16)((v.u + 0x7FFFu + ((v.u >> 16) & 1u)) >> 16);
}
__device__ __forceinline__ float bf2f(u16 h) {
    union { unsigned u; float f; } v; v.u = ((unsigned)h) << 16;
    return v.f;
}

// MFMA via inline asm (sidesteps builtin operand-type ambiguity; HK-proven path).
__device__ __forceinline__ void mfma16(f32x4& d, bf16x8 a, bf16x8 b) {
    asm("v_mfma_f32_16x16x32_bf16 %0, %1, %2, %0" : "+v"(d) : "v"(a), "v"(b));
}

// async global->LDS, 16B per lane. lds base must be wave-uniform; HW adds lane*16.
__device__ __forceinline__ void gload_lds16(const u16* g, u16* lds) {
    __builtin_amdgcn_global_load_lds((__attribute__((address_space(1))) void*)g,
                                     (__attribute__((address_space(3))) void*)lds,
                                     16, 0, 0);
}

// ---------------- fp32 -> bf16 convert ----------------
__global__ __launch_bounds__(256) void cvt_kernel(const float* __restrict__ in,
                                                  u16* __restrict__ out, int n4) {
    int i = blockIdx.x * blockDim.x + threadIdx.x;
    int stride = gridDim.x * blockDim.x;
    for (; i < n4; i += stride) {
        float4 v = ((const float4*)in)[i];
        ushort4 o;
        o.x = f2bf(v.x); o.y = f2bf(v.y); o.z = f2bf(v.z); o.w = f2bf(v.w);
        ((ushort4*)out)[i] = o;
    }
}

// ---------------- RoPE cos/sin table: tbl[pos*64 + j] = {cos, sin} ----------------
__global__ __launch_bounds__(256) void rope_table_kernel(float2* __restrict__ tbl) {
    int i = blockIdx.x * blockDim.x + threadIdx.x;
    if (i >= S * 64) return;
    int p = i >> 6, j = i & 63;
    float inv = powf(10000.0f, -(float)j / 64.0f);
    float a = (float)p * inv;
    tbl[i] = make_float2(cosf(a), sinf(a));
}

// ---------------- RoPE in-place on bf16 [S][nh][128], pair (d, d+64) ----------------
__global__ __launch_bounds__(256) void rope_kernel(u16* __restrict__ X,
                                                   const float2* __restrict__ tbl,
                                                   int nh, float scale) {
    int i = blockIdx.x * blockDim.x + threadIdx.x;
    int total = S * nh * 64;
    if (i >= total) return;
    int dd = i & 63;
    int t2 = i >> 6;
    int hh = t2 % nh;
    int s  = t2 / nh;
    size_t base = (size_t)s * nh * HD + (size_t)hh * HD + dd;
    float x1 = bf2f(X[base]);
    float x2 = bf2f(X[base + 64]);
    float2 cs = tbl[(s << 6) + dd];
    X[base]      = f2bf((x1 * cs.x - x2 * cs.y) * scale);
    X[base + 64] = f2bf((x2 * cs.x + x1 * cs.y) * scale);
}

// ---------------- GEMM: C = A(MxK) * Bt(NxK)^T, bf16 in, fp32 accum ----------------
// MODE 0: C bf16 row-major [M][N]   MODE 1: C f32 row-major   MODE 2: C^T bf16 [N][M]
template<int MODE>
__global__ __launch_bounds__(256)
void gemm_bt(const u16* __restrict__ A, const u16* __restrict__ Bt,
             void* __restrict__ Cv, int M, int N, int K, int lda, int ldb, int ldc) {
    __shared__ u16 Al[128][64];
    __shared__ u16 Bl[128][64];
    const int t = threadIdx.x;
    const int w = t >> 6, l = t & 63;
    const int r16 = l & 15, g4 = l >> 4;
    const int m0 = blockIdx.y * 128, n0 = blockIdx.x * 128;
    const int wr = (w >> 1) * 64, wc = (w & 1) * 64;

    f32x4 acc[4][4];
#pragma unroll
    for (int i = 0; i < 4; ++i)
#pragma unroll
        for (int j = 0; j < 4; ++j) acc[i][j] = f32x4{0.f, 0.f, 0.f, 0.f};

    for (int kt = 0; kt < K; kt += 64) {
#pragma unroll
        for (int i = 0; i < 4; ++i) {  // A tile: 128x64 bf16 = 1024 x 16B chunks
            int c = i * 256 + t;
            gload_lds16(A + (size_t)(m0 + (c >> 3)) * lda + kt + ((c & 7) << 3),
                        &Al[0][0] + ((i * 256 + w * 64) << 3));
        }
#pragma unroll
        for (int i = 0; i < 4; ++i) {
            int c = i * 256 + t;
            gload_lds16(Bt + (size_t)(n0 + (c >> 3)) * ldb + kt + ((c & 7) << 3),
                        &Bl[0][0] + ((i * 256 + w * 64) << 3));
        }
        asm volatile("s_waitcnt vmcnt(0)" ::: "memory");
        __syncthreads();

#pragma unroll
        for (int kk = 0; kk < 2; ++kk) {
            bf16x8 af[4], bfr[4];
#pragma unroll
            for (int mi = 0; mi < 4; ++mi)
                af[mi] = *(const bf16x8*)&Al[wr + mi * 16 + r16][kk * 32 + g4 * 8];
#pragma unroll
            for (int ni = 0; ni < 4; ++ni)
                bfr[ni] = *(const bf16x8*)&Bl[wc + ni * 16 + r16][kk * 32 + g4 * 8];
#pragma unroll
            for (int mi = 0; mi < 4; ++mi)
#pragma unroll
                for (int ni = 0; ni < 4; ++ni)
                    mfma16(acc[mi][ni], af[mi], bfr[ni]);
        }
        __syncthreads();
    }

    const int rb = g4 * 4;
#pragma unroll
    for (int mi = 0; mi < 4; ++mi) {
#pragma unroll
        for (int ni = 0; ni < 4; ++ni) {
            const int n = n0 + wc + ni * 16 + r16;
            const int mbase = m0 + wr + mi * 16 + rb;
            if constexpr (MODE == 0) {
                u16* C = (u16*)Cv;
#pragma unroll
                for (int j = 0; j < 4; ++j)
                    C[(size_t)(mbase + j) * ldc + n] = f2bf(acc[mi][ni][j]);
            } else if constexpr (MODE == 1) {
                float* C = (float*)Cv;
#pragma unroll
                for (int j = 0; j < 4; ++j)
                    C[(size_t)(mbase + j) * ldc + n] = acc[mi][ni][j];
            } else {  // transposed bf16: Ct[n][mbase..mbase+3], 8B store
                u16* C = (u16*)Cv;
                ushort4 v;
                v.x = f2bf(acc[mi][ni][0]); v.y = f2bf(acc[mi][ni][1]);
                v.z = f2bf(acc[mi][ni][2]); v.w = f2bf(acc[mi][ni][3]);
                *(ushort4*)&C[(size_t)n * ldc + mbase] = v;
            }
        }
    }
}

// ---------------- causal GQA flash attention ----------------
// grid: (S/64, NH). 4 waves; wave w owns q-rows [q0+16w, q0+16w+16). KV tile = 64.
// Q,K: bf16 [S][heads*128] (RoPE'd; Q pre-scaled by HD^-0.5). Vt: bf16 [NKV*128][S].
__global__ __launch_bounds__(256)
void attn_fwd(const u16* __restrict__ Q, const u16* __restrict__ K,
              const u16* __restrict__ Vt, u16* __restrict__ O) {
    __shared__ u16 Kl[64][128];
    __shared__ u16 Vl[128][64];
    __shared__ u16 Pl[4][16][64];

    const int t = threadIdx.x;
    const int w = t >> 6, l = t & 63;
    const int r16 = l & 15, g4 = l >> 4;
    const int h = blockIdx.y;
    const int q0 = blockIdx.x * 64;
    const int kvh = h >> 2;  // groups = 4

    // Q fragments: A-operand layout (row = l%16, k = 8*(l>>4)+i), k over d=128
    const int qrow = q0 + w * 16 + r16;
    bf16x8 qf[4];
#pragma unroll
    for (int kg = 0; kg < 4; ++kg)
        qf[kg] = *(const bf16x8*)&Q[(size_t)qrow * (NH * HD) + h * HD + kg * 32 + g4 * 8];

    f32x4 acco[8];
#pragma unroll
    for (int i = 0; i < 8; ++i) acco[i] = f32x4{0.f, 0.f, 0.f, 0.f};
    float mrun[4], lrun[4];
#pragma unroll
    for (int j = 0; j < 4; ++j) { mrun[j] = -3.0e38f; lrun[j] = 0.f; }

    const int nt = blockIdx.x + 1;  // causal: kv tiles 0 .. q0/64
    for (int tk = 0; tk < nt; ++tk) {
        const int kv0 = tk * 64;
        // stage K tile [64][128] (16KB) and Vt tile [128][64] (16KB)
#pragma unroll
        for (int i = 0; i < 4; ++i) {
            int c = i * 256 + t;
            gload_lds16(K + (size_t)(kv0 + (c >> 4)) * (NKV * HD) + kvh * HD + ((c & 15) << 3),
                        &Kl[0][0] + ((i * 256 + w * 64) << 3));
        }
#pragma unroll
        for (int i = 0; i < 4; ++i) {
            int c = i * 256 + t;
            gload_lds16(Vt + (size_t)(kvh * HD + (c >> 3)) * S + kv0 + ((c & 7) << 3),
                        &Vl[0][0] + ((i * 256 + w * 64) << 3));
        }
        asm volatile("s_waitcnt vmcnt(0)" ::: "memory");
        __syncthreads();

        // QK^T: S-tile 16(q) x 64(k) per wave
        f32x4 sc[4];
#pragma unroll
        for (int ni = 0; ni < 4; ++ni) sc[ni] = f32x4{0.f, 0.f, 0.f, 0.f};
#pragma unroll
        for (int kg = 0; kg < 4; ++kg) {
#pragma unroll
            for (int ni = 0; ni < 4; ++ni) {
                bf16x8 kf = *(const bf16x8*)&Kl[ni * 16 + r16][kg * 32 + g4 * 8];
                mfma16(sc[ni], qf[kg], kf);
            }
        }

        // mask + online softmax (fp32). D layout: row=(l>>4)*4+j, col=l&15.
        float fac[4];
#pragma unroll
        for (int j = 0; j < 4; ++j) {
            const int qg = q0 + w * 16 + g4 * 4 + j;
#pragma unroll
            for (int ni = 0; ni < 4; ++ni) {
                const int kcol = kv0 + ni * 16 + r16;
                if (kcol > qg) sc[ni][j] = -3.0e38f;
            }
            float v = fmaxf(fmaxf(sc[0][j], sc[1][j]), fmaxf(sc[2][j], sc[3][j]));
            v = fmaxf(v, __shfl_xor(v, 1, 16));
            v = fmaxf(v, __shfl_xor(v, 2, 16));
            v = fmaxf(v, __shfl_xor(v, 4, 16));
            v = fmaxf(v, __shfl_xor(v, 8, 16));
            const float nm = fmaxf(mrun[j], v);
            fac[j] = expf(mrun[j] - nm);
            mrun[j] = nm;
            float p0 = expf(sc[0][j] - nm);
            float p1 = expf(sc[1][j] - nm);
            float p2 = expf(sc[2][j] - nm);
            float p3 = expf(sc[3][j] - nm);
            sc[0][j] = p0; sc[1][j] = p1; sc[2][j] = p2; sc[3][j] = p3;
            float s2 = (p0 + p1) + (p2 + p3);
            s2 += __shfl_xor(s2, 1, 16);
            s2 += __shfl_xor(s2, 2, 16);
            s2 += __shfl_xor(s2, 4, 16);
            s2 += __shfl_xor(s2, 8, 16);
            lrun[j] = lrun[j] * fac[j] + s2;
        }

        // P (D-layout) -> LDS -> reload in A-operand layout
#pragma unroll
        for (int ni = 0; ni < 4; ++ni)
#pragma unroll
            for (int j = 0; j < 4; ++j)
                Pl[w][g4 * 4 + j][ni * 16 + r16] = f2bf(sc[ni][j]);
        asm volatile("s_waitcnt lgkmcnt(0)" ::: "memory");

#pragma unroll
        for (int i = 0; i < 8; ++i)
#pragma unroll
            for (int j = 0; j < 4; ++j) acco[i][j] *= fac[j];

        bf16x8 pf0 = *(const bf16x8*)&Pl[w][r16][g4 * 8];
        bf16x8 pf1 = *(const bf16x8*)&Pl[w][r16][32 + g4 * 8];
#pragma unroll
        for (int ni = 0; ni < 8; ++ni) {
            bf16x8 v0 = *(const bf16x8*)&Vl[ni * 16 + r16][g4 * 8];
            mfma16(acco[ni], pf0, v0);
            bf16x8 v1 = *(const bf16x8*)&Vl[ni * 16 + r16][32 + g4 * 8];
            mfma16(acco[ni], pf1, v1);
        }
        __syncthreads();
    }

    // O[s][h*128+d] bf16
#pragma unroll
    for (int ni = 0; ni < 8; ++ni) {
#pragma unroll
        for (int j = 0; j < 4; ++j) {
            const int qg = q0 + w * 16 + g4 * 4 + j;
            O[(size_t)qg * (NH * HD) + h * HD + ni * 16 + r16] = f2bf(acco[ni][j] / lrun[j]);
        }
    }
}

// ---------------- launch ----------------
extern "C" void kernel_launch(void* const* d_in, const int* in_sizes, int n_in,
                              void* d_out, int out_size, void* d_ws, size_t ws_size,
                              hipStream_t stream) {
    const float* X  = (const float*)d_in[0];
    // d_in[1] = position_ids (arange(S) by construction; index used directly)
    const float* Wq = (const float*)d_in[2];
    const float* Wk = (const float*)d_in[3];
    const float* Wv = (const float*)d_in[4];
    const float* Wo = (const float*)d_in[5];

    char* ws = (char*)d_ws;
    // byte offsets, all 256B aligned
    u16*    Xbf  = (u16*)(ws + 0);           // 2048x4096 bf16 = 16,777,216
    u16*    Wqbf = (u16*)(ws + 16777216);    // 4096x4096 bf16 = 33,554,432
    u16*    Wkbf = (u16*)(ws + 50331648);    // 1024x4096 bf16 =  8,388,608
    u16*    Wvbf = (u16*)(ws + 58720256);    // 1024x4096 bf16 =  8,388,608
    u16*    Wobf = (u16*)(ws + 67108864);    // 4096x4096 bf16 = 33,554,432
    u16*    Qbf  = (u16*)(ws + 100663296);   // 2048x4096 bf16 = 16,777,216
    u16*    Kbf  = (u16*)(ws + 117440512);   // 2048x1024 bf16 =  4,194,304
    u16*    Vtbf = (u16*)(ws + 121634816);   // 1024x2048 bf16 =  4,194,304 (V^T)
    u16*    Obf  = (u16*)(ws + 125829120);   // 2048x4096 bf16 = 16,777,216
    float2* tbl  = (float2*)(ws + 142606336);// 2048x64 float2 =  1,048,576
    if (ws_size < 143654912ull) return;      // need ~137 MiB scratch

    dim3 blk(256);

    // fp32 -> bf16
    cvt_kernel<<<2048, blk, 0, stream>>>(X,  Xbf,  S * DM / 4);
    cvt_kernel<<<2048, blk, 0, stream>>>(Wq, Wqbf, NH * HD * DM / 4);
    cvt_kernel<<<1024, blk, 0, stream>>>(Wk, Wkbf, NKV * HD * DM / 4);
    cvt_kernel<<<1024, blk, 0, stream>>>(Wv, Wvbf, NKV * HD * DM / 4);
    cvt_kernel<<<2048, blk, 0, stream>>>(Wo, Wobf, DM * NH * HD / 4);
    rope_table_kernel<<<(S * 64 + 255) / 256, blk, 0, stream>>>(tbl);

    // projections: C = X * W^T
    gemm_bt<0><<<dim3(DM / 128, S / 128), blk, 0, stream>>>(
        Xbf, Wqbf, Qbf, S, NH * HD, DM, DM, DM, NH * HD);
    gemm_bt<0><<<dim3((NKV * HD) / 128, S / 128), blk, 0, stream>>>(
        Xbf, Wkbf, Kbf, S, NKV * HD, DM, DM, DM, NKV * HD);
    gemm_bt<2><<<dim3((NKV * HD) / 128, S / 128), blk, 0, stream>>>(
        Xbf, Wvbf, Vtbf, S, NKV * HD, DM, DM, DM, S);  // writes V^T [1024][2048]

    // RoPE (Q also folds in HD^-0.5 attention scale)
    rope_kernel<<<(S * NH * 64 + 255) / 256, blk, 0, stream>>>(
        Qbf, tbl, NH, 0.08838834764831845f);
    rope_kernel<<<(S * NKV * 64 + 255) / 256, blk, 0, stream>>>(Kbf, tbl, NKV, 1.0f);

    // causal GQA flash attention
    attn_fwd<<<dim3(S / 64, NH), blk, 0, stream>>>(Qbf, Kbf, Vtbf, Obf);

    // output projection -> fp32
    gemm_bt<1><<<dim3(DM / 128, S / 128), blk, 0, stream>>>(
        Obf, Wobf, d_out, S, DM, NH * HD, NH * HD, NH * HD, DM);
}

// Round 2
// 386.123 us; speedup vs baseline: 1.8601x; 1.8601x over previous
//
#include <hip/hip_runtime.h>
#include <stdint.h>

typedef unsigned short u16;
typedef __attribute__((ext_vector_type(4))) float f32x4;
typedef __attribute__((ext_vector_type(8))) short bf16x8;

static constexpr int S   = 2048;
static constexpr int DM  = 4096;  // model dim
static constexpr int NH  = 32;    // query heads
static constexpr int NKV = 8;     // kv heads
static constexpr int HD  = 128;   // head dim
static constexpr int LDQ = 5120;  // QK buffer row stride (Q 4096 | K 1024)

__device__ __forceinline__ u16 f2bf(float f) {
    union { float f; unsigned u; } v; v.f = f;
    return (u16)((v.u + 0x7FFFu + ((v.u >> 16) & 1u)) >> 16);
}
__device__ __forceinline__ float bf2f(u16 h) {
    union { unsigned u; float f; } v; v.u = ((unsigned)h) << 16;
    return v.f;
}

__device__ __forceinline__ void mfma16(f32x4& d, bf16x8 a, bf16x8 b) {
    asm("v_mfma_f32_16x16x32_bf16 %0, %1, %2, %0" : "+v"(d) : "v"(a), "v"(b));
}

// async global->LDS, 16B/lane. LDS base is wave-uniform; HW adds lane*16.
__device__ __forceinline__ void gload_lds16(const u16* g, u16* lds) {
    __builtin_amdgcn_global_load_lds((__attribute__((address_space(1))) void*)g,
                                     (__attribute__((address_space(3))) void*)lds,
                                     16, 0, 0);
}

// ---------------- fp32 -> bf16 converts ----------------
__global__ __launch_bounds__(256) void cvt_kernel(const float* __restrict__ in,
                                                  u16* __restrict__ out, int n4) {
    int i = blockIdx.x * blockDim.x + threadIdx.x;
    int stride = gridDim.x * blockDim.x;
    for (; i < n4; i += stride) {
        float4 v = ((const float4*)in)[i];
        ushort4 o;
        o.x = f2bf(v.x); o.y = f2bf(v.y); o.z = f2bf(v.z); o.w = f2bf(v.w);
        ((ushort4*)out)[i] = o;
    }
}

// fused Wq|Wk|Wv -> contiguous bf16 [6144][4096]
__global__ __launch_bounds__(256) void cvt_qkv(const float* __restrict__ Wq,
                                               const float* __restrict__ Wk,
                                               const float* __restrict__ Wv,
                                               u16* __restrict__ out) {
    const int n4 = 6144 * 4096 / 4;
    int i = blockIdx.x * blockDim.x + threadIdx.x;
    int stride = gridDim.x * blockDim.x;
    for (; i < n4; i += stride) {
        float4 v;
        if (i < 4194304)       v = ((const float4*)Wq)[i];
        else if (i < 5242880)  v = ((const float4*)Wk)[i - 4194304];
        else                   v = ((const float4*)Wv)[i - 5242880];
        ushort4 o;
        o.x = f2bf(v.x); o.y = f2bf(v.y); o.z = f2bf(v.z); o.w = f2bf(v.w);
        ((ushort4*)out)[i] = o;
    }
}

// ---------------- RoPE cos/sin table: tbl[pos*64 + j] = {cos, sin} ----------------
__global__ __launch_bounds__(256) void rope_table_kernel(float2* __restrict__ tbl) {
    int i = blockIdx.x * blockDim.x + threadIdx.x;
    if (i >= S * 64) return;
    int p = i >> 6, j = i & 63;
    float inv = powf(10000.0f, -(float)j / 64.0f);
    float a = (float)p * inv;
    tbl[i] = make_float2(cosf(a), sinf(a));
}

// ---------------- RoPE in-place on bf16, row stride ld, pair (d, d+64) ----------------
__global__ __launch_bounds__(256) void rope_kernel(u16* __restrict__ X,
                                                   const float2* __restrict__ tbl,
                                                   int nh, int ld, float scale) {
    int i = blockIdx.x * blockDim.x + threadIdx.x;
    int total = S * nh * 64;
    if (i >= total) return;
    int dd = i & 63;
    int t2 = i >> 6;
    int hh = t2 % nh;
    int s  = t2 / nh;
    size_t base = (size_t)s * ld + (size_t)hh * HD + dd;
    float x1 = bf2f(X[base]);
    float x2 = bf2f(X[base + 64]);
    float2 cs = tbl[(s << 6) + dd];
    X[base]      = f2bf((x1 * cs.x - x2 * cs.y) * scale);
    X[base + 64] = f2bf((x2 * cs.x + x1 * cs.y) * scale);
}

// ---------------- generic GEMM: C = A(MxK) * Bt(NxK)^T, f32 out ----------------
template<int MODE>  // 1: f32 row-major
__global__ __launch_bounds__(256)
void gemm_bt(const u16* __restrict__ A, const u16* __restrict__ Bt,
             void* __restrict__ Cv, int M, int N, int K, int lda, int ldb, int ldc) {
    __shared__ u16 Al[128][64];
    __shared__ u16 Bl[128][64];
    const int t = threadIdx.x;
    const int w = t >> 6, l = t & 63;
    const int r16 = l & 15, g4 = l >> 4;
    const int m0 = blockIdx.y * 128, n0 = blockIdx.x * 128;
    const int wr = (w >> 1) * 64, wc = (w & 1) * 64;

    f32x4 acc[4][4];
#pragma unroll
    for (int i = 0; i < 4; ++i)
#pragma unroll
        for (int j = 0; j < 4; ++j) acc[i][j] = f32x4{0.f, 0.f, 0.f, 0.f};

    for (int kt = 0; kt < K; kt += 64) {
#pragma unroll
        for (int i = 0; i < 4; ++i) {
            int c = i * 256 + t;
            gload_lds16(A + (size_t)(m0 + (c >> 3)) * lda + kt + ((c & 7) << 3),
                        &Al[0][0] + ((i * 256 + w * 64) << 3));
        }
#pragma unroll
        for (int i = 0; i < 4; ++i) {
            int c = i * 256 + t;
            gload_lds16(Bt + (size_t)(n0 + (c >> 3)) * ldb + kt + ((c & 7) << 3),
                        &Bl[0][0] + ((i * 256 + w * 64) << 3));
        }
        asm volatile("s_waitcnt vmcnt(0)" ::: "memory");
        __syncthreads();

#pragma unroll
        for (int kk = 0; kk < 2; ++kk) {
            bf16x8 af[4], bfr[4];
#pragma unroll
            for (int mi = 0; mi < 4; ++mi)
                af[mi] = *(const bf16x8*)&Al[wr + mi * 16 + r16][kk * 32 + g4 * 8];
#pragma unroll
            for (int ni = 0; ni < 4; ++ni)
                bfr[ni] = *(const bf16x8*)&Bl[wc + ni * 16 + r16][kk * 32 + g4 * 8];
#pragma unroll
            for (int mi = 0; mi < 4; ++mi)
#pragma unroll
                for (int ni = 0; ni < 4; ++ni)
                    mfma16(acc[mi][ni], af[mi], bfr[ni]);
        }
        __syncthreads();
    }

    const int rb = g4 * 4;
#pragma unroll
    for (int mi = 0; mi < 4; ++mi) {
#pragma unroll
        for (int ni = 0; ni < 4; ++ni) {
            const int n = n0 + wc + ni * 16 + r16;
            const int mbase = m0 + wr + mi * 16 + rb;
            float* C = (float*)Cv;
#pragma unroll
            for (int j = 0; j < 4; ++j)
                C[(size_t)(mbase + j) * ldc + n] = acc[mi][ni][j];
        }
    }
}

// ---------------- fused QKV GEMM: X[2048][4096] * Wqkv[6144][4096]^T ----------------
// n < 5120 -> Cqk[m][n] bf16 (stride 5120).  n >= 5120 -> Vt[n-5120][m] bf16 (stride 2048).
__global__ __launch_bounds__(256)
void gemm_qkv(const u16* __restrict__ A, const u16* __restrict__ Bt,
              u16* __restrict__ Cqk, u16* __restrict__ Vt) {
    __shared__ u16 Al[128][64];
    __shared__ u16 Bl[128][64];
    const int t = threadIdx.x;
    const int w = t >> 6, l = t & 63;
    const int r16 = l & 15, g4 = l >> 4;
    const int m0 = blockIdx.y * 128, n0 = blockIdx.x * 128;
    const int wr = (w >> 1) * 64, wc = (w & 1) * 64;

    f32x4 acc[4][4];
#pragma unroll
    for (int i = 0; i < 4; ++i)
#pragma unroll
        for (int j = 0; j < 4; ++j) acc[i][j] = f32x4{0.f, 0.f, 0.f, 0.f};

    for (int kt = 0; kt < DM; kt += 64) {
#pragma unroll
        for (int i = 0; i < 4; ++i) {
            int c = i * 256 + t;
            gload_lds16(A + (size_t)(m0 + (c >> 3)) * DM + kt + ((c & 7) << 3),
                        &Al[0][0] + ((i * 256 + w * 64) << 3));
        }
#pragma unroll
        for (int i = 0; i < 4; ++i) {
            int c = i * 256 + t;
            gload_lds16(Bt + (size_t)(n0 + (c >> 3)) * DM + kt + ((c & 7) << 3),
                        &Bl[0][0] + ((i * 256 + w * 64) << 3));
        }
        asm volatile("s_waitcnt vmcnt(0)" ::: "memory");
        __syncthreads();

#pragma unroll
        for (int kk = 0; kk < 2; ++kk) {
            bf16x8 af[4], bfr[4];
#pragma unroll
            for (int mi = 0; mi < 4; ++mi)
                af[mi] = *(const bf16x8*)&Al[wr + mi * 16 + r16][kk * 32 + g4 * 8];
#pragma unroll
            for (int ni = 0; ni < 4; ++ni)
                bfr[ni] = *(const bf16x8*)&Bl[wc + ni * 16 + r16][kk * 32 + g4 * 8];
#pragma unroll
            for (int mi = 0; mi < 4; ++mi)
#pragma unroll
                for (int ni = 0; ni < 4; ++ni)
                    mfma16(acc[mi][ni], af[mi], bfr[ni]);
        }
        __syncthreads();
    }

    const int rb = g4 * 4;
    if (n0 < 5120) {  // Q|K region, row-major
#pragma unroll
        for (int mi = 0; mi < 4; ++mi)
#pragma unroll
            for (int ni = 0; ni < 4; ++ni) {
                const int n = n0 + wc + ni * 16 + r16;
                const int mbase = m0 + wr + mi * 16 + rb;
#pragma unroll
                for (int j = 0; j < 4; ++j)
                    Cqk[(size_t)(mbase + j) * LDQ + n] = f2bf(acc[mi][ni][j]);
            }
    } else {          // V region, transposed into Vt[1024][2048]
#pragma unroll
        for (int mi = 0; mi < 4; ++mi)
#pragma unroll
            for (int ni = 0; ni < 4; ++ni) {
                const int n = n0 + wc + ni * 16 + r16 - 5120;
                const int mbase = m0 + wr + mi * 16 + rb;
                ushort4 v;
                v.x = f2bf(acc[mi][ni][0]); v.y = f2bf(acc[mi][ni][1]);
                v.z = f2bf(acc[mi][ni][2]); v.w = f2bf(acc[mi][ni][3]);
                *(ushort4*)&Vt[(size_t)n * S + mbase] = v;
            }
    }
}

// ---------------- causal GQA flash attention ----------------
// grid (16, 32): block p handles q-tiles p and 31-p (balanced causal work = 33 kv-tiles).
// Q in QK[s][h*128], K in QK[s][4096+kvh*128] (stride 5120, RoPE'd; Q pre-scaled by
// log2(e)/sqrt(128) so softmax runs in exp2 domain). Vt bf16 [NKV*128][S].
// All K/V/P LDS accesses XOR-swizzled (byte ^= (row&7)<<4); K/V staged via
// pre-swizzled global source since global_load_lds writes linearly.
__global__ __launch_bounds__(256, 2)
void attn_fwd(const u16* __restrict__ QK, const u16* __restrict__ Vt,
              u16* __restrict__ O) {
    __shared__ u16 Kl[2][64 * 128];   // 2 x 16KB
    __shared__ u16 Vl[2][128 * 64];   // 2 x 16KB
    __shared__ u16 Pl[4 * 16 * 64];   // 8KB, per-wave 2KB

    const int t = threadIdx.x;
    const int w = t >> 6, l = t & 63;
    const int r16 = l & 15, g4 = l >> 4;
    const int h = blockIdx.y;
    const int kvh = h >> 2;
    const int p = blockIdx.x;
    const int q0A = p * 64, q0B = (31 - p) * 64;
    const int ntA = p + 1, ntB = 32 - p;

    const u16* Kg = QK + 4096 + kvh * HD;
    const u16* Vg = Vt + (size_t)(kvh * HD) * S;
    u16* Pb = &Pl[w * 1024];

    // Q fragments for both tiles (A-operand: row=l%16, k=8*(l>>4)+i)
    bf16x8 qfA[4], qfB[4];
    {
        const u16* Qg = QK + h * HD;
        const size_t qrA = (size_t)(q0A + w * 16 + r16) * LDQ;
        const size_t qrB = (size_t)(q0B + w * 16 + r16) * LDQ;
#pragma unroll
        for (int kg = 0; kg < 4; ++kg) {
            qfA[kg] = *(const bf16x8*)&Qg[qrA + kg * 32 + g4 * 8];
            qfB[kg] = *(const bf16x8*)&Qg[qrB + kg * 32 + g4 * 8];
        }
    }

    f32x4 accA[8], accB[8];
    float mA[4], lA[4], mB[4], lB[4];
#pragma unroll
    for (int i = 0; i < 8; ++i) { accA[i] = f32x4{0,0,0,0}; accB[i] = f32x4{0,0,0,0}; }
#pragma unroll
    for (int j = 0; j < 4; ++j) { mA[j] = -3.0e38f; lA[j] = 0.f; mB[j] = -3.0e38f; lB[j] = 0.f; }

    // stage KV tile tk into buffer b, source pre-swizzled (slot ^= row&7)
    auto stage = [&](int tk, int b) {
        const int kv0 = tk * 64;
#pragma unroll
        for (int i = 0; i < 4; ++i) {  // K: 64 rows x 256B (16 slots)
            int c = i * 256 + t;
            int r = c >> 4, s = (c & 15) ^ (r & 7);
            gload_lds16(Kg + (size_t)(kv0 + r) * LDQ + (s << 3),
                        &Kl[b][0] + ((i * 256 + w * 64) << 3));
        }
#pragma unroll
        for (int i = 0; i < 4; ++i) {  // Vt: 128 rows x 128B (8 slots)
            int c = i * 256 + t;
            int r = c >> 3, s = (c & 7) ^ (r & 7);
            gload_lds16(Vg + (size_t)r * S + kv0 + (s << 3),
                        &Vl[b][0] + ((i * 256 + w * 64) << 3));
        }
    };

    auto compute = [&](f32x4 (&acco)[8], float (&mrun)[4], float (&lrun)[4],
                       const bf16x8 (&qf)[4], int q0, int tk, bool maskit, int b) {
        const int kv0 = tk * 64;
        const u16* Kb = &Kl[b][0];
        const u16* Vb = &Vl[b][0];

        // QK^T: 16 q-rows x 64 k-cols per wave (swizzled K reads)
        f32x4 sc[4];
#pragma unroll
        for (int ni = 0; ni < 4; ++ni) sc[ni] = f32x4{0,0,0,0};
#pragma unroll
        for (int kg = 0; kg < 4; ++kg) {
#pragma unroll
            for (int ni = 0; ni < 4; ++ni) {
                int row = ni * 16 + r16;
                int bb = (row * 256 + kg * 64 + g4 * 16) ^ ((row & 7) << 4);
                bf16x8 kf = *(const bf16x8*)((const char*)Kb + bb);
                mfma16(sc[ni], qf[kg], kf);
            }
        }

        // online softmax in exp2 domain. D layout: row=(l>>4)*4+j, col=l&15.
        float vmax[4];
        bool grow = false;
#pragma unroll
        for (int j = 0; j < 4; ++j) {
            if (maskit) {
                const int qg = q0 + w * 16 + g4 * 4 + j;
#pragma unroll
                for (int ni = 0; ni < 4; ++ni)
                    if (kv0 + ni * 16 + r16 > qg) sc[ni][j] = -3.0e38f;
            }
            float v = fmaxf(fmaxf(sc[0][j], sc[1][j]), fmaxf(sc[2][j], sc[3][j]));
            v = fmaxf(v, __shfl_xor(v, 1, 16));
            v = fmaxf(v, __shfl_xor(v, 2, 16));
            v = fmaxf(v, __shfl_xor(v, 4, 16));
            v = fmaxf(v, __shfl_xor(v, 8, 16));
            vmax[j] = v;
            grow = grow || (v > mrun[j] + 11.5f);  // defer-max (THR=8 nats in log2)
        }
        float fac[4] = {1.f, 1.f, 1.f, 1.f};
        if (__any(grow)) {
#pragma unroll
            for (int j = 0; j < 4; ++j) {
                float nm = fmaxf(mrun[j], vmax[j]);
                fac[j] = exp2f(mrun[j] - nm);
                mrun[j] = nm;
            }
#pragma unroll
            for (int i = 0; i < 8; ++i)
#pragma unroll
                for (int j = 0; j < 4; ++j) acco[i][j] *= fac[j];
        }
#pragma unroll
        for (int j = 0; j < 4; ++j) {
            float p0 = exp2f(sc[0][j] - mrun[j]);
            float p1 = exp2f(sc[1][j] - mrun[j]);
            float p2 = exp2f(sc[2][j] - mrun[j]);
            float p3 = exp2f(sc[3][j] - mrun[j]);
            sc[0][j] = p0; sc[1][j] = p1; sc[2][j] = p2; sc[3][j] = p3;
            float s2 = (p0 + p1) + (p2 + p3);
            s2 += __shfl_xor(s2, 1, 16);
            s2 += __shfl_xor(s2, 2, 16);
            s2 += __shfl_xor(s2, 4, 16);
            s2 += __shfl_xor(s2, 8, 16);
            lrun[j] = lrun[j] * fac[j] + s2;
        }

        // P (D-layout) -> swizzled LDS -> A-operand layout
#pragma unroll
        for (int ni = 0; ni < 4; ++ni)
#pragma unroll
            for (int j = 0; j < 4; ++j) {
                int row = g4 * 4 + j;
                int bb = (row * 128 + ((ni * 16 + r16) << 1)) ^ ((row & 7) << 4);
                *(u16*)((char*)Pb + bb) = f2bf(sc[ni][j]);
            }
        asm volatile("s_waitcnt lgkmcnt(0)" ::: "memory");
        __builtin_amdgcn_sched_barrier(0);

        int pb0 = (r16 * 128 + g4 * 16) ^ ((r16 & 7) << 4);
        bf16x8 pf0 = *(const bf16x8*)((const char*)Pb + pb0);
        bf16x8 pf1 = *(const bf16x8*)((const char*)Pb + (pb0 ^ 64));
#pragma unroll
        for (int ni = 0; ni < 8; ++ni) {
            int row = ni * 16 + r16;
            int bb = (row * 128 + g4 * 16) ^ ((row & 7) << 4);
            bf16x8 v0 = *(const bf16x8*)((const char*)Vb + bb);
            mfma16(acco[ni], pf0, v0);
            bf16x8 v1 = *(const bf16x8*)((const char*)Vb + (bb ^ 64));
            mfma16(acco[ni], pf1, v1);
        }
    };

    auto epilogue = [&](f32x4 (&acco)[8], float (&lrun)[4], int q0) {
        float rl[4];
#pragma unroll
        for (int j = 0; j < 4; ++j) rl[j] = 1.0f / lrun[j];
#pragma unroll
        for (int ni = 0; ni < 8; ++ni)
#pragma unroll
            for (int j = 0; j < 4; ++j) {
                const int qg = q0 + w * 16 + g4 * 4 + j;
                O[(size_t)qg * DM + h * HD + ni * 16 + r16] = f2bf(acco[ni][j] * rl[j]);
            }
    };

    // ---- 2-phase pipelined loops: stage(next) || compute(cur) ----
    stage(0, 0);
    asm volatile("s_waitcnt vmcnt(0)" ::: "memory");
    __syncthreads();
    int buf = 0;

    for (int tk = 0; tk < ntA; ++tk) {
        if (tk + 1 < ntA) stage(tk + 1, buf ^ 1);
        else              stage(0, buf ^ 1);        // prefetch B's first tile
        compute(accA, mA, lA, qfA, q0A, tk, tk == ntA - 1, buf);
        asm volatile("s_waitcnt vmcnt(0)" ::: "memory");
        __syncthreads();
        buf ^= 1;
    }
    epilogue(accA, lA, q0A);

    for (int tk = 0; tk < ntB; ++tk) {
        if (tk + 1 < ntB) stage(tk + 1, buf ^ 1);
        compute(accB, mB, lB, qfB, q0B, tk, tk == ntB - 1, buf);
        asm volatile("s_waitcnt vmcnt(0)" ::: "memory");
        __syncthreads();
        buf ^= 1;
    }
    epilogue(accB, lB, q0B);
}

// ---------------- launch ----------------
extern "C" void kernel_launch(void* const* d_in, const int* in_sizes, int n_in,
                              void* d_out, int out_size, void* d_ws, size_t ws_size,
                              hipStream_t stream) {
    const float* X  = (const float*)d_in[0];
    // d_in[1] = position_ids (arange(S) by construction)
    const float* Wq = (const float*)d_in[2];
    const float* Wk = (const float*)d_in[3];
    const float* Wv = (const float*)d_in[4];
    const float* Wo = (const float*)d_in[5];

    char* ws = (char*)d_ws;
    u16*    Xbf  = (u16*)(ws + 0);            // 2048x4096 bf16 = 16,777,216
    u16*    Wqkv = (u16*)(ws + 16777216);     // 6144x4096 bf16 = 50,331,648
    u16*    Wobf = (u16*)(ws + 67108864);     // 4096x4096 bf16 = 33,554,432
    u16*    QKb  = (u16*)(ws + 100663296);    // 2048x5120 bf16 = 20,971,520
    u16*    Vtbf = (u16*)(ws + 121634816);    // 1024x2048 bf16 =  4,194,304 (V^T)
    u16*    Obf  = (u16*)(ws + 125829120);    // 2048x4096 bf16 = 16,777,216
    float2* tbl  = (float2*)(ws + 142606336); // 2048x64 float2 =  1,048,576
    if (ws_size < 143654912ull) return;

    dim3 blk(256);

    cvt_kernel<<<2048, blk, 0, stream>>>(X,  Xbf,  S * DM / 4);
    cvt_qkv<<<2048, blk, 0, stream>>>(Wq, Wk, Wv, Wqkv);
    cvt_kernel<<<2048, blk, 0, stream>>>(Wo, Wobf, DM * DM / 4);
    rope_table_kernel<<<(S * 64 + 255) / 256, blk, 0, stream>>>(tbl);

    // fused QKV projection (Q|K row-major stride 5120; V transposed)
    gemm_qkv<<<dim3(48, 16), blk, 0, stream>>>(Xbf, Wqkv, QKb, Vtbf);

    // RoPE; Q also folds in log2(e)*HD^-0.5 so softmax runs in exp2 domain
    rope_kernel<<<(S * NH * 64 + 255) / 256, blk, 0, stream>>>(
        QKb, tbl, NH, LDQ, 0.08838834764831845f * 1.4426950408889634f);
    rope_kernel<<<(S * NKV * 64 + 255) / 256, blk, 0, stream>>>(
        QKb + 4096, tbl, NKV, LDQ, 1.0f);

    attn_fwd<<<dim3(16, NH), blk, 0, stream>>>(QKb, Vtbf, Obf);

    // output projection -> fp32
    gemm_bt<1><<<dim3(DM / 128, S / 128), blk, 0, stream>>>(
        Obf, Wobf, d_out, S, DM, DM, DM, DM, DM);
}